// Round 4
// baseline (1369.074 us; speedup 1.0000x reference)
//
#include <hip/hip_runtime.h>

// MoE top-2, B=8 T=4096 D=512 H=1536 E=8.
// R9: keep R6's ffn structure (4-indep-block TLP beat both pipelining
// attempts R7/R8). Attack non-GEMM costs instead:
//  (a) class-partitioned per-expert lists ([primary|secondary], gate2 split
//      into count+place dispatches) -> ffn2 runs per class: cls0 stores out
//      (pass0) / RMW, cls1 plain RMW (pass0-cls0 initialized every row).
//      Deletes prt buffer AND combine kernel: out-path 603->469 MB.
//  (b) LDS trimmed to exactly 32KiB in ffn1/ffn2 (wgs/toks staging dropped,
//      epilogue reads wgtl/tokl directly) -> 5 blocks/CU instead of 4.
//  (c) 3 cvt launches fused into 1.

#define N_TOK 32768
#define DIM   512
#define HID   1536
#define NE    8
#define MTS   256   // max 128-row tiles per expert (worst case ne=32768)

typedef __attribute__((ext_vector_type(8))) short  short8;
typedef __attribute__((ext_vector_type(4))) float  floatx4;

#define MFMA(a,b,c) __builtin_amdgcn_mfma_f32_16x16x32_bf16(a,b,c,0,0,0)

__device__ __forceinline__ unsigned short f2bf(float f) {
  unsigned int u = __float_as_uint(f);
  u += 0x7fffu + ((u >> 16) & 1u);
  return (unsigned short)(u >> 16);
}
__device__ __forceinline__ unsigned pk2(float a, float b) {
  return (unsigned)f2bf(a) | ((unsigned)f2bf(b) << 16);
}
// async global->LDS, 16B per lane; dst = wave-uniform base + lane*16
__device__ __forceinline__ void gl_lds16(const unsigned short* g, unsigned short* l) {
  __builtin_amdgcn_global_load_lds(
      (const __attribute__((address_space(1))) unsigned int*)g,
      (__attribute__((address_space(3))) unsigned int*)l, 16, 0, 0);
}

// ---------------- fp32 -> bf16 weight conversion (w1|w3|w2 fused) ----------------
__global__ void __launch_bounds__(256) cvt3_kernel(const float* __restrict__ w1,
                                                   const float* __restrict__ w3,
                                                   const float* __restrict__ w2,
                                                   unsigned short* __restrict__ w1b,
                                                   unsigned short* __restrict__ w3b,
                                                   unsigned short* __restrict__ w2b,
                                                   int n4) {
  int i = blockIdx.x * 256 + threadIdx.x;
  const float* s; unsigned short* d; int j = i;
  if (j < n4)          { s = w1; d = w1b; }
  else if (j < 2 * n4) { s = w3; d = w3b; j -= n4; }
  else                 { s = w2; d = w2b; j -= 2 * n4; }
  float4 v = ((const float4*)s)[j];
  uint2 o; o.x = pk2(v.x, v.y); o.y = pk2(v.z, v.w);
  ((uint2*)d)[j] = o;
}

// ------------- gate phase 1: logits (fp64), top-2, softmax; also x->bf16 -------------
__global__ void __launch_bounds__(256) gate1_kernel(const float* __restrict__ x,
                                                    const float* __restrict__ gw,
                                                    unsigned short* __restrict__ xb,
                                                    unsigned* __restrict__ eidx,
                                                    float* __restrict__ wts) {
  int lane = threadIdx.x & 63;
  int wave = threadIdx.x >> 6;
  int t = blockIdx.x * 4 + wave;

  const float4* xp = (const float4*)(x + (size_t)t * DIM + lane * 8);
  float4 x0 = xp[0], x1 = xp[1];

  uint4 o; o.x = pk2(x0.x, x0.y); o.y = pk2(x0.z, x0.w);
  o.z = pk2(x1.x, x1.y); o.w = pk2(x1.z, x1.w);
  *(uint4*)(xb + (size_t)t * DIM + lane * 8) = o;

  double p[NE];
#pragma unroll
  for (int e = 0; e < NE; ++e) {
    const float4* gp = (const float4*)(gw + e * DIM + lane * 8);
    float4 g0 = gp[0], g1 = gp[1];
    p[e] = (double)x0.x * g0.x + (double)x0.y * g0.y + (double)x0.z * g0.z + (double)x0.w * g0.w
         + (double)x1.x * g1.x + (double)x1.y * g1.y + (double)x1.z * g1.z + (double)x1.w * g1.w;
  }
#pragma unroll
  for (int m = 1; m < 64; m <<= 1) {
#pragma unroll
    for (int e = 0; e < NE; ++e) p[e] += __shfl_xor(p[e], m);
  }
  if (lane == 0) {
    double m1 = -1e300, m2 = -1e300; int i1 = 0, i2 = 0;
#pragma unroll
    for (int e = 0; e < NE; ++e) {
      double v = p[e];
      if (v > m1) { m2 = m1; i2 = i1; m1 = v; i1 = e; }
      else if (v > m2) { m2 = v; i2 = e; }
    }
    float e2 = __expf((float)(m2 - m1));
    float wa = 1.f / (1.f + e2);
    eidx[t] = (unsigned)i1 | ((unsigned)i2 << 8);
    wts[t]  = wa;
  }
}

// -------- gate phase 2a: per-expert class counts (cntP[e]=cnt[e], cntS[e]=cnt[8+e]) ----
__global__ void __launch_bounds__(256) gate2a_kernel(const unsigned* __restrict__ eidx,
                                                     int* __restrict__ cnt) {
  __shared__ unsigned histP[NE], histS[NE];
  int tid = threadIdx.x;
  if (tid < NE) { histP[tid] = 0; histS[tid] = 0; }
  __syncthreads();
  int t0 = blockIdx.x * 1024;
#pragma unroll
  for (int i = 0; i < 4; ++i) {
    unsigned pk = eidx[t0 + tid + i * 256];
    atomicAdd(&histP[pk & 0xff], 1u);
    atomicAdd(&histS[(pk >> 8) & 0xff], 1u);
  }
  __syncthreads();
  if (tid < NE) {
    atomicAdd(&cnt[tid], (int)histP[tid]);
    atomicAdd(&cnt[NE + tid], (int)histS[tid]);
  }
}

// -------- gate phase 2b: place entries. list layout per expert: [P | S].
// cursors: curP[e]=cnt[16+e], curS[e]=cnt[24+e]. tokl S entries tagged bit31.
__global__ void __launch_bounds__(256) gate2b_kernel(const unsigned* __restrict__ eidx,
                                                     const float* __restrict__ wts,
                                                     int* __restrict__ tokl,
                                                     float* __restrict__ wgtl,
                                                     int* __restrict__ cnt) {
  __shared__ unsigned histP[NE], histS[NE];
  __shared__ unsigned baseP[NE], baseS[NE];
  int tid = threadIdx.x;
  if (tid < NE) { histP[tid] = 0; histS[tid] = 0; }
  __syncthreads();
  int t0 = blockIdx.x * 1024;
  unsigned pk[4]; float wv[4];
#pragma unroll
  for (int i = 0; i < 4; ++i) {
    int t = t0 + tid + i * 256;
    pk[i] = eidx[t]; wv[i] = wts[t];
    atomicAdd(&histP[pk[i] & 0xff], 1u);
    atomicAdd(&histS[(pk[i] >> 8) & 0xff], 1u);
  }
  __syncthreads();
  if (tid < NE) {
    baseP[tid] = (unsigned)atomicAdd(&cnt[2 * NE + tid], (int)histP[tid]);
    baseS[tid] = (unsigned)cnt[tid] + (unsigned)atomicAdd(&cnt[3 * NE + tid], (int)histS[tid]);
    histP[tid] = 0; histS[tid] = 0;
  }
  __syncthreads();
#pragma unroll
  for (int i = 0; i < 4; ++i) {
    int t = t0 + tid + i * 256;
    int e1 = pk[i] & 0xff, e2 = (pk[i] >> 8) & 0xff;
    unsigned p1 = baseP[e1] + atomicAdd(&histP[e1], 1u);
    tokl[e1 * N_TOK + p1] = t; wgtl[e1 * N_TOK + p1] = wv[i];
    unsigned p2 = baseS[e2] + atomicAdd(&histS[e2], 1u);
    tokl[e2 * N_TOK + p2] = t | (int)0x80000000; wgtl[e2 * N_TOK + p2] = 1.f - wv[i];
  }
}

// ---------------- GEMM1: Hs = wgt * silu(X w1^T) * (X w3^T), bf16 ----------------
// tile: 128 tokens x 64 h-cols. Bs = [w1 rows 0..63 | w3 rows 0..63].
// wave (wm,wn): tokens wm*64.., h-cols wn*32..; u/v accs match lanes -> reg silu.
// LDS exactly 32KiB -> 5 blocks/CU.
__global__ void __launch_bounds__(256, 5) ffn1_kernel(
    const unsigned short* __restrict__ xb,
    const unsigned short* __restrict__ w1b,
    const unsigned short* __restrict__ w3b,
    const int* __restrict__ tokl, const float* __restrict__ wgtl,
    const int* __restrict__ cnt,
    unsigned short* __restrict__ Hs,
    int h0base, int P, int NT) {
  int e  = blockIdx.x & 7;
  int t  = blockIdx.x >> 3;
  int nt = t % NT, mt = t / NT;
  int ne = cnt[e] + cnt[NE + e];
  int m0 = mt * 128;
  if (m0 >= ne) return;
  int offs = 0;
#pragma unroll
  for (int i = 0; i < NE; ++i) offs += (i < e) ? (cnt[i] + cnt[NE + i]) : 0;

  __shared__ __align__(16) unsigned short As[128 * 64];   // XOR-swizzled chunks
  __shared__ __align__(16) unsigned short Bs[128 * 64];

  int tid = threadIdx.x, w = tid >> 6, lane = tid & 63;
  int quad = lane >> 4, l16 = lane & 15;
  int wm = w >> 1, wn = w & 1;

  int rl = lane >> 3, cc = (lane & 7) ^ rl;   // staging: XOR-swizzled source chunk
  const unsigned short* pa[4];
#pragma unroll
  for (int i = 0; i < 4; ++i) {
    int r = m0 + 32 * w + 8 * i + rl;
    int tok = tokl[e * N_TOK + (r < ne ? r : m0)] & 0x7fffffff;
    pa[i] = xb + (size_t)tok * DIM + cc * 8;
  }
  // B rows regular: one base pointer, const strides
  const unsigned short* wsrc = (w < 2) ? w1b : w3b;
  const unsigned short* pb0 =
      wsrc + ((size_t)e * HID + h0base + nt * 64 + ((32 * w) & 63) + rl) * DIM + cc * 8;

  floatx4 u[4][2], v[4][2];
#pragma unroll
  for (int i = 0; i < 4; ++i)
#pragma unroll
    for (int j = 0; j < 2; ++j) { u[i][j] = (floatx4){0,0,0,0}; v[i][j] = (floatx4){0,0,0,0}; }

  for (int k0 = 0; k0 < DIM; k0 += 64) {
#pragma unroll
    for (int i = 0; i < 4; ++i) {
      gl_lds16(pa[i], &As[(32 * w + 8 * i) * 64]);
      gl_lds16(pb0 + (size_t)i * 8 * DIM, &Bs[(32 * w + 8 * i) * 64]);
      pa[i] += 64;
    }
    pb0 += 64;
    __syncthreads();
#pragma unroll
    for (int kk = 0; kk < 2; ++kk) {
      int s = ((4 * kk + quad) ^ (l16 & 7)) * 8;   // all row bases ≡ 0 mod 8
      short8 a[4], b1[2], b3[2];
#pragma unroll
      for (int i = 0; i < 4; ++i)
        a[i] = *(const short8*)&As[(wm * 64 + i * 16 + l16) * 64 + s];
#pragma unroll
      for (int j = 0; j < 2; ++j) {
        b1[j] = *(const short8*)&Bs[(wn * 32 + j * 16 + l16) * 64 + s];
        b3[j] = *(const short8*)&Bs[(64 + wn * 32 + j * 16 + l16) * 64 + s];
      }
#pragma unroll
      for (int i = 0; i < 4; ++i)
#pragma unroll
        for (int j = 0; j < 2; ++j) {
          u[i][j] = MFMA(a[i], b1[j], u[i][j]);
          v[i][j] = MFMA(a[i], b3[j], v[i][j]);
        }
    }
    __syncthreads();
  }

  // ---- epilogue: in-register silu, pack to LDS (reuse As), coalesced store ----
  // weight read directly from wgtl (L1 broadcast; 16 loads/thread, epilogue-only)
#pragma unroll
  for (int i = 0; i < 4; ++i)
#pragma unroll
    for (int r = 0; r < 4; ++r) {
      int tr = wm * 64 + i * 16 + quad * 4 + r;
      float wg = wgtl[e * N_TOK + m0 + tr];
#pragma unroll
      for (int j = 0; j < 2; ++j) {
        int hc = wn * 32 + j * 16 + l16;
        float uu = u[i][j][r], vv = v[i][j][r];
        float h = (uu / (1.f + __expf(-uu))) * vv * wg;
        As[tr * 64 + hc] = f2bf(h);
      }
    }
  __syncthreads();
  {
    int row = tid >> 1, half = tid & 1;
    if (m0 + row < ne) {
      const unsigned short* s = &As[row * 64 + half * 32];
      unsigned short* d = Hs + (size_t)(offs + m0 + row) * P + nt * 64 + half * 32;
#pragma unroll
      for (int j = 0; j < 4; ++j) *(uint4*)(d + j * 8) = *(const uint4*)(s + j * 8);
    }
  }
}

// ---------------- GEMM2: out = Hs @ w2^T (gate weight already folded) ----------
// tile: M=128 tokens x N=128 d-cols, BK=64, K=P. LDS exactly 32KiB -> 5 blocks/CU.
// cls=0: primary rows [0,neP): store if first else RMW.
// cls=1: secondary rows [neP,neAll): plain RMW (pass0-cls0 initialized all rows).
__global__ void __launch_bounds__(256, 5) ffn2_kernel(
    const unsigned short* __restrict__ Hs,
    const unsigned short* __restrict__ w2b,
    const int* __restrict__ tokl, const int* __restrict__ cnt,
    float* __restrict__ out,
    int h0base, int P, int first, int cls) {
  int e  = blockIdx.x & 7;
  int t  = blockIdx.x >> 3;
  int nt = t & 3, mt = t >> 2;
  int neP = cnt[e];
  int neAll = neP + cnt[NE + e];
  int m0 = mt * 128;
  if (cls == 0) { if (m0 >= neP) return; }
  else          { if (m0 >= neAll || m0 + 128 <= neP) return; }
  int offs = 0;
#pragma unroll
  for (int i = 0; i < NE; ++i) offs += (i < e) ? (cnt[i] + cnt[NE + i]) : 0;

  __shared__ __align__(16) unsigned short As[128 * 64];
  __shared__ __align__(16) unsigned short Bs[128 * 64];

  int tid = threadIdx.x, w = tid >> 6, lane = tid & 63;
  int quad = lane >> 4, l16 = lane & 15;
  int wm = w >> 1, wn = w & 1;

  int rl = lane >> 3, cc = (lane & 7) ^ rl;
  int dbase = nt * 128;
  const unsigned short* pa0 = Hs + (size_t)(offs + m0 + 32 * w + rl) * P + cc * 8;
  const unsigned short* pb0 =
      w2b + ((size_t)e * DIM + dbase + 32 * w + rl) * HID + h0base + cc * 8;

  floatx4 acc[4][4];
#pragma unroll
  for (int i = 0; i < 4; ++i)
#pragma unroll
    for (int j = 0; j < 4; ++j) acc[i][j] = (floatx4){0, 0, 0, 0};

  for (int k0 = 0; k0 < P; k0 += 64) {
#pragma unroll
    for (int i = 0; i < 4; ++i) {
      gl_lds16(pa0 + (size_t)i * 8 * P,   &As[(32 * w + 8 * i) * 64]);
      gl_lds16(pb0 + (size_t)i * 8 * HID, &Bs[(32 * w + 8 * i) * 64]);
    }
    pa0 += 64; pb0 += 64;
    __syncthreads();
#pragma unroll
    for (int kk = 0; kk < 2; ++kk) {
      int s = ((4 * kk + quad) ^ (l16 & 7)) * 8;
      short8 a[4], b[4];
#pragma unroll
      for (int i = 0; i < 4; ++i) {
        a[i] = *(const short8*)&As[(wm * 64 + i * 16 + l16) * 64 + s];
        b[i] = *(const short8*)&Bs[(wn * 64 + i * 16 + l16) * 64 + s];
      }
#pragma unroll
      for (int i = 0; i < 4; ++i)
#pragma unroll
        for (int j = 0; j < 4; ++j)
          acc[i][j] = MFMA(a[i], b[j], acc[i][j]);
    }
    __syncthreads();
  }

#pragma unroll
  for (int i = 0; i < 4; ++i)
#pragma unroll
    for (int r = 0; r < 4; ++r) {
      int row = wm * 64 + i * 16 + quad * 4 + r;
      int gr = m0 + row;
      int tk = tokl[e * N_TOK + gr];
      bool doit = cls ? (gr < neAll && tk < 0) : (gr < neP);
      if (!doit) continue;
      float* dst = out + (size_t)(tk & 0x7fffffff) * DIM + dbase + wn * 64 + l16;
      if (first && cls == 0) {
#pragma unroll
        for (int j = 0; j < 4; ++j) dst[j * 16] = acc[i][j][r];
      } else {
#pragma unroll
        for (int j = 0; j < 4; ++j) dst[j * 16] += acc[i][j][r];
      }
    }
}

extern "C" void kernel_launch(void* const* d_in, const int* in_sizes, int n_in,
                              void* d_out, int out_size, void* d_ws, size_t ws_size,
                              hipStream_t stream) {
  const float* x  = (const float*)d_in[0];
  const float* gw = (const float*)d_in[1];
  const float* w1 = (const float*)d_in[2];
  const float* w3 = (const float*)d_in[3];
  const float* w2 = (const float*)d_in[4];
  float* out = (float*)d_out;

  const size_t NW = (size_t)NE * HID * DIM;
  char* p = (char*)d_ws;
  unsigned short* w1b = (unsigned short*)p;  p += NW * 2;
  unsigned short* w3b = (unsigned short*)p;  p += NW * 2;
  unsigned short* w2b = (unsigned short*)p;  p += NW * 2;
  unsigned short* xb  = (unsigned short*)p;  p += (size_t)N_TOK * DIM * 2;
  int*      tokl = (int*)p;       p += (size_t)NE * N_TOK * 4;
  float*    wgtl = (float*)p;     p += (size_t)NE * N_TOK * 4;
  unsigned* eidx = (unsigned*)p;  p += (size_t)N_TOK * 4;
  float*    wts  = (float*)p;     p += (size_t)N_TOK * 4;
  int*      cnt  = (int*)p;       p += 256;   // [cntP|cntS|curP|curS] x 8
  unsigned short* Hs = (unsigned short*)p;
  size_t fixed = (size_t)(p - (char*)d_ws);
  if (ws_size < fixed) return;
  size_t avail = ws_size - fixed;

  const int cands[5] = {1536, 768, 512, 384, 256};
  int P = 0;
  for (int i = 0; i < 5; ++i)
    if ((size_t)(2 * N_TOK + 128) * cands[i] * 2 <= avail) { P = cands[i]; break; }
  if (!P) return;

  hipMemsetAsync(cnt, 0, 256, stream);

  int n4 = (int)(NW / 4);
  cvt3_kernel<<<3 * n4 / 256, 256, 0, stream>>>(w1, w3, w2, w1b, w3b, w2b, n4);

  gate1_kernel<<<N_TOK / 4, 256, 0, stream>>>(x, gw, xb, eidx, wts);
  gate2a_kernel<<<N_TOK / 1024, 256, 0, stream>>>(eidx, cnt);
  gate2b_kernel<<<N_TOK / 1024, 256, 0, stream>>>(eidx, wts, tokl, wgtl, cnt);

  int pass = 0;
  for (int h0 = 0; h0 < HID; h0 += P) {
    int NT = P / 64;
    ffn1_kernel<<<8 * MTS * NT, 256, 0, stream>>>(xb, w1b, w3b, tokl, wgtl, cnt, Hs, h0, P, NT);
    ffn2_kernel<<<8 * MTS * 4, 256, 0, stream>>>(Hs, w2b, tokl, cnt, out, h0, P, pass == 0, 0);
    ffn2_kernel<<<8 * MTS * 4, 256, 0, stream>>>(Hs, w2b, tokl, cnt, out, h0, P, 0, 1);
    ++pass;
  }
}

// Round 5
// 663.530 us; speedup vs baseline: 2.0633x; 2.0633x over previous
//
#include <hip/hip_runtime.h>

// MoE top-2, B=8 T=4096 D=512 H=1536 E=8.
// R10: R9 structure with the poison removed. R9's __launch_bounds__(256,5)
// forced VGPR 64->48 and spilled the MFMA accumulators to scratch
// (WRITE_SIZE 98MB -> 1.25GB/dispatch, ffn1 486us). Bounds back to (256,4)
// -- the known-good 64-VGPR allocation; the 32KiB LDS trim still allows a
// 5th block/CU opportunistically if regs stay <=64. Keeping R9's verified
// wins: class-partitioned lists ([primary|secondary] per expert; ffn2 runs
// per class: cls0 store/RMW, cls1 plain RMW) -> no prt buffer, no combine
// kernel, out-path 603->469MB; fused cvt; epilogue reads wgtl/tokl direct.

#define N_TOK 32768
#define DIM   512
#define HID   1536
#define NE    8
#define MTS   256   // max 128-row tiles per expert (worst case ne=32768)

typedef __attribute__((ext_vector_type(8))) short  short8;
typedef __attribute__((ext_vector_type(4))) float  floatx4;

#define MFMA(a,b,c) __builtin_amdgcn_mfma_f32_16x16x32_bf16(a,b,c,0,0,0)

__device__ __forceinline__ unsigned short f2bf(float f) {
  unsigned int u = __float_as_uint(f);
  u += 0x7fffu + ((u >> 16) & 1u);
  return (unsigned short)(u >> 16);
}
__device__ __forceinline__ unsigned pk2(float a, float b) {
  return (unsigned)f2bf(a) | ((unsigned)f2bf(b) << 16);
}
// async global->LDS, 16B per lane; dst = wave-uniform base + lane*16
__device__ __forceinline__ void gl_lds16(const unsigned short* g, unsigned short* l) {
  __builtin_amdgcn_global_load_lds(
      (const __attribute__((address_space(1))) unsigned int*)g,
      (__attribute__((address_space(3))) unsigned int*)l, 16, 0, 0);
}

// ---------------- fp32 -> bf16 weight conversion (w1|w3|w2 fused) ----------------
__global__ void __launch_bounds__(256) cvt3_kernel(const float* __restrict__ w1,
                                                   const float* __restrict__ w3,
                                                   const float* __restrict__ w2,
                                                   unsigned short* __restrict__ w1b,
                                                   unsigned short* __restrict__ w3b,
                                                   unsigned short* __restrict__ w2b,
                                                   int n4) {
  int i = blockIdx.x * 256 + threadIdx.x;
  const float* s; unsigned short* d; int j = i;
  if (j < n4)          { s = w1; d = w1b; }
  else if (j < 2 * n4) { s = w3; d = w3b; j -= n4; }
  else                 { s = w2; d = w2b; j -= 2 * n4; }
  float4 v = ((const float4*)s)[j];
  uint2 o; o.x = pk2(v.x, v.y); o.y = pk2(v.z, v.w);
  ((uint2*)d)[j] = o;
}

// ------------- gate phase 1: logits (fp64), top-2, softmax; also x->bf16 -------------
__global__ void __launch_bounds__(256) gate1_kernel(const float* __restrict__ x,
                                                    const float* __restrict__ gw,
                                                    unsigned short* __restrict__ xb,
                                                    unsigned* __restrict__ eidx,
                                                    float* __restrict__ wts) {
  int lane = threadIdx.x & 63;
  int wave = threadIdx.x >> 6;
  int t = blockIdx.x * 4 + wave;

  const float4* xp = (const float4*)(x + (size_t)t * DIM + lane * 8);
  float4 x0 = xp[0], x1 = xp[1];

  uint4 o; o.x = pk2(x0.x, x0.y); o.y = pk2(x0.z, x0.w);
  o.z = pk2(x1.x, x1.y); o.w = pk2(x1.z, x1.w);
  *(uint4*)(xb + (size_t)t * DIM + lane * 8) = o;

  double p[NE];
#pragma unroll
  for (int e = 0; e < NE; ++e) {
    const float4* gp = (const float4*)(gw + e * DIM + lane * 8);
    float4 g0 = gp[0], g1 = gp[1];
    p[e] = (double)x0.x * g0.x + (double)x0.y * g0.y + (double)x0.z * g0.z + (double)x0.w * g0.w
         + (double)x1.x * g1.x + (double)x1.y * g1.y + (double)x1.z * g1.z + (double)x1.w * g1.w;
  }
#pragma unroll
  for (int m = 1; m < 64; m <<= 1) {
#pragma unroll
    for (int e = 0; e < NE; ++e) p[e] += __shfl_xor(p[e], m);
  }
  if (lane == 0) {
    double m1 = -1e300, m2 = -1e300; int i1 = 0, i2 = 0;
#pragma unroll
    for (int e = 0; e < NE; ++e) {
      double v = p[e];
      if (v > m1) { m2 = m1; i2 = i1; m1 = v; i1 = e; }
      else if (v > m2) { m2 = v; i2 = e; }
    }
    float e2 = __expf((float)(m2 - m1));
    float wa = 1.f / (1.f + e2);
    eidx[t] = (unsigned)i1 | ((unsigned)i2 << 8);
    wts[t]  = wa;
  }
}

// -------- gate phase 2a: per-expert class counts (cntP[e]=cnt[e], cntS[e]=cnt[8+e]) ----
__global__ void __launch_bounds__(256) gate2a_kernel(const unsigned* __restrict__ eidx,
                                                     int* __restrict__ cnt) {
  __shared__ unsigned histP[NE], histS[NE];
  int tid = threadIdx.x;
  if (tid < NE) { histP[tid] = 0; histS[tid] = 0; }
  __syncthreads();
  int t0 = blockIdx.x * 1024;
#pragma unroll
  for (int i = 0; i < 4; ++i) {
    unsigned pk = eidx[t0 + tid + i * 256];
    atomicAdd(&histP[pk & 0xff], 1u);
    atomicAdd(&histS[(pk >> 8) & 0xff], 1u);
  }
  __syncthreads();
  if (tid < NE) {
    atomicAdd(&cnt[tid], (int)histP[tid]);
    atomicAdd(&cnt[NE + tid], (int)histS[tid]);
  }
}

// -------- gate phase 2b: place entries. list layout per expert: [P | S].
// cursors: curP[e]=cnt[16+e], curS[e]=cnt[24+e]. tokl S entries tagged bit31.
__global__ void __launch_bounds__(256) gate2b_kernel(const unsigned* __restrict__ eidx,
                                                     const float* __restrict__ wts,
                                                     int* __restrict__ tokl,
                                                     float* __restrict__ wgtl,
                                                     int* __restrict__ cnt) {
  __shared__ unsigned histP[NE], histS[NE];
  __shared__ unsigned baseP[NE], baseS[NE];
  int tid = threadIdx.x;
  if (tid < NE) { histP[tid] = 0; histS[tid] = 0; }
  __syncthreads();
  int t0 = blockIdx.x * 1024;
  unsigned pk[4]; float wv[4];
#pragma unroll
  for (int i = 0; i < 4; ++i) {
    int t = t0 + tid + i * 256;
    pk[i] = eidx[t]; wv[i] = wts[t];
    atomicAdd(&histP[pk[i] & 0xff], 1u);
    atomicAdd(&histS[(pk[i] >> 8) & 0xff], 1u);
  }
  __syncthreads();
  if (tid < NE) {
    baseP[tid] = (unsigned)atomicAdd(&cnt[2 * NE + tid], (int)histP[tid]);
    baseS[tid] = (unsigned)cnt[tid] + (unsigned)atomicAdd(&cnt[3 * NE + tid], (int)histS[tid]);
    histP[tid] = 0; histS[tid] = 0;
  }
  __syncthreads();
#pragma unroll
  for (int i = 0; i < 4; ++i) {
    int t = t0 + tid + i * 256;
    int e1 = pk[i] & 0xff, e2 = (pk[i] >> 8) & 0xff;
    unsigned p1 = baseP[e1] + atomicAdd(&histP[e1], 1u);
    tokl[e1 * N_TOK + p1] = t; wgtl[e1 * N_TOK + p1] = wv[i];
    unsigned p2 = baseS[e2] + atomicAdd(&histS[e2], 1u);
    tokl[e2 * N_TOK + p2] = t | (int)0x80000000; wgtl[e2 * N_TOK + p2] = 1.f - wv[i];
  }
}

// ---------------- GEMM1: Hs = wgt * silu(X w1^T) * (X w3^T), bf16 ----------------
// tile: 128 tokens x 64 h-cols. Bs = [w1 rows 0..63 | w3 rows 0..63].
// wave (wm,wn): tokens wm*64.., h-cols wn*32..; u/v accs match lanes -> reg silu.
// LDS exactly 32KiB; bounds (256,4): 64-VGPR alloc (no spill), 5th block free.
__global__ void __launch_bounds__(256, 4) ffn1_kernel(
    const unsigned short* __restrict__ xb,
    const unsigned short* __restrict__ w1b,
    const unsigned short* __restrict__ w3b,
    const int* __restrict__ tokl, const float* __restrict__ wgtl,
    const int* __restrict__ cnt,
    unsigned short* __restrict__ Hs,
    int h0base, int P, int NT) {
  int e  = blockIdx.x & 7;
  int t  = blockIdx.x >> 3;
  int nt = t % NT, mt = t / NT;
  int ne = cnt[e] + cnt[NE + e];
  int m0 = mt * 128;
  if (m0 >= ne) return;
  int offs = 0;
#pragma unroll
  for (int i = 0; i < NE; ++i) offs += (i < e) ? (cnt[i] + cnt[NE + i]) : 0;

  __shared__ __align__(16) unsigned short As[128 * 64];   // XOR-swizzled chunks
  __shared__ __align__(16) unsigned short Bs[128 * 64];

  int tid = threadIdx.x, w = tid >> 6, lane = tid & 63;
  int quad = lane >> 4, l16 = lane & 15;
  int wm = w >> 1, wn = w & 1;

  int rl = lane >> 3, cc = (lane & 7) ^ rl;   // staging: XOR-swizzled source chunk
  const unsigned short* pa[4];
#pragma unroll
  for (int i = 0; i < 4; ++i) {
    int r = m0 + 32 * w + 8 * i + rl;
    int tok = tokl[e * N_TOK + (r < ne ? r : m0)] & 0x7fffffff;
    pa[i] = xb + (size_t)tok * DIM + cc * 8;
  }
  // B rows regular: one base pointer, const strides
  const unsigned short* wsrc = (w < 2) ? w1b : w3b;
  const unsigned short* pb0 =
      wsrc + ((size_t)e * HID + h0base + nt * 64 + ((32 * w) & 63) + rl) * DIM + cc * 8;

  floatx4 u[4][2], v[4][2];
#pragma unroll
  for (int i = 0; i < 4; ++i)
#pragma unroll
    for (int j = 0; j < 2; ++j) { u[i][j] = (floatx4){0,0,0,0}; v[i][j] = (floatx4){0,0,0,0}; }

  for (int k0 = 0; k0 < DIM; k0 += 64) {
#pragma unroll
    for (int i = 0; i < 4; ++i) {
      gl_lds16(pa[i], &As[(32 * w + 8 * i) * 64]);
      gl_lds16(pb0 + (size_t)i * 8 * DIM, &Bs[(32 * w + 8 * i) * 64]);
      pa[i] += 64;
    }
    pb0 += 64;
    __syncthreads();
#pragma unroll
    for (int kk = 0; kk < 2; ++kk) {
      int s = ((4 * kk + quad) ^ (l16 & 7)) * 8;   // all row bases ≡ 0 mod 8
      short8 a[4], b1[2], b3[2];
#pragma unroll
      for (int i = 0; i < 4; ++i)
        a[i] = *(const short8*)&As[(wm * 64 + i * 16 + l16) * 64 + s];
#pragma unroll
      for (int j = 0; j < 2; ++j) {
        b1[j] = *(const short8*)&Bs[(wn * 32 + j * 16 + l16) * 64 + s];
        b3[j] = *(const short8*)&Bs[(64 + wn * 32 + j * 16 + l16) * 64 + s];
      }
#pragma unroll
      for (int i = 0; i < 4; ++i)
#pragma unroll
        for (int j = 0; j < 2; ++j) {
          u[i][j] = MFMA(a[i], b1[j], u[i][j]);
          v[i][j] = MFMA(a[i], b3[j], v[i][j]);
        }
    }
    __syncthreads();
  }

  // ---- epilogue: in-register silu, pack to LDS (reuse As), coalesced store ----
  // weight read directly from wgtl (L1 broadcast; epilogue-only)
#pragma unroll
  for (int i = 0; i < 4; ++i)
#pragma unroll
    for (int r = 0; r < 4; ++r) {
      int tr = wm * 64 + i * 16 + quad * 4 + r;
      float wg = wgtl[e * N_TOK + m0 + tr];
#pragma unroll
      for (int j = 0; j < 2; ++j) {
        int hc = wn * 32 + j * 16 + l16;
        float uu = u[i][j][r], vv = v[i][j][r];
        float h = (uu / (1.f + __expf(-uu))) * vv * wg;
        As[tr * 64 + hc] = f2bf(h);
      }
    }
  __syncthreads();
  {
    int row = tid >> 1, half = tid & 1;
    if (m0 + row < ne) {
      const unsigned short* s = &As[row * 64 + half * 32];
      unsigned short* d = Hs + (size_t)(offs + m0 + row) * P + nt * 64 + half * 32;
#pragma unroll
      for (int j = 0; j < 4; ++j) *(uint4*)(d + j * 8) = *(const uint4*)(s + j * 8);
    }
  }
}

// ---------------- GEMM2: out = Hs @ w2^T (gate weight already folded) ----------
// tile: M=128 tokens x N=128 d-cols, BK=64, K=P. LDS exactly 32KiB.
// cls=0: primary rows [0,neP): store if first else RMW.
// cls=1: secondary rows [neP,neAll): plain RMW (pass0-cls0 initialized all rows).
__global__ void __launch_bounds__(256, 4) ffn2_kernel(
    const unsigned short* __restrict__ Hs,
    const unsigned short* __restrict__ w2b,
    const int* __restrict__ tokl, const int* __restrict__ cnt,
    float* __restrict__ out,
    int h0base, int P, int first, int cls) {
  int e  = blockIdx.x & 7;
  int t  = blockIdx.x >> 3;
  int nt = t & 3, mt = t >> 2;
  int neP = cnt[e];
  int neAll = neP + cnt[NE + e];
  int m0 = mt * 128;
  if (cls == 0) { if (m0 >= neP) return; }
  else          { if (m0 >= neAll || m0 + 128 <= neP) return; }
  int offs = 0;
#pragma unroll
  for (int i = 0; i < NE; ++i) offs += (i < e) ? (cnt[i] + cnt[NE + i]) : 0;

  __shared__ __align__(16) unsigned short As[128 * 64];
  __shared__ __align__(16) unsigned short Bs[128 * 64];

  int tid = threadIdx.x, w = tid >> 6, lane = tid & 63;
  int quad = lane >> 4, l16 = lane & 15;
  int wm = w >> 1, wn = w & 1;

  int rl = lane >> 3, cc = (lane & 7) ^ rl;
  int dbase = nt * 128;
  const unsigned short* pa0 = Hs + (size_t)(offs + m0 + 32 * w + rl) * P + cc * 8;
  const unsigned short* pb0 =
      w2b + ((size_t)e * DIM + dbase + 32 * w + rl) * HID + h0base + cc * 8;

  floatx4 acc[4][4];
#pragma unroll
  for (int i = 0; i < 4; ++i)
#pragma unroll
    for (int j = 0; j < 4; ++j) acc[i][j] = (floatx4){0, 0, 0, 0};

  for (int k0 = 0; k0 < P; k0 += 64) {
#pragma unroll
    for (int i = 0; i < 4; ++i) {
      gl_lds16(pa0 + (size_t)i * 8 * P,   &As[(32 * w + 8 * i) * 64]);
      gl_lds16(pb0 + (size_t)i * 8 * HID, &Bs[(32 * w + 8 * i) * 64]);
    }
    pa0 += 64; pb0 += 64;
    __syncthreads();
#pragma unroll
    for (int kk = 0; kk < 2; ++kk) {
      int s = ((4 * kk + quad) ^ (l16 & 7)) * 8;
      short8 a[4], b[4];
#pragma unroll
      for (int i = 0; i < 4; ++i) {
        a[i] = *(const short8*)&As[(wm * 64 + i * 16 + l16) * 64 + s];
        b[i] = *(const short8*)&Bs[(wn * 64 + i * 16 + l16) * 64 + s];
      }
#pragma unroll
      for (int i = 0; i < 4; ++i)
#pragma unroll
        for (int j = 0; j < 4; ++j)
          acc[i][j] = MFMA(a[i], b[j], acc[i][j]);
    }
    __syncthreads();
  }

#pragma unroll
  for (int i = 0; i < 4; ++i)
#pragma unroll
    for (int r = 0; r < 4; ++r) {
      int row = wm * 64 + i * 16 + quad * 4 + r;
      int gr = m0 + row;
      int tk = tokl[e * N_TOK + gr];
      bool doit = cls ? (gr < neAll && tk < 0) : (gr < neP);
      if (!doit) continue;
      float* dst = out + (size_t)(tk & 0x7fffffff) * DIM + dbase + wn * 64 + l16;
      if (first && cls == 0) {
#pragma unroll
        for (int j = 0; j < 4; ++j) dst[j * 16] = acc[i][j][r];
      } else {
#pragma unroll
        for (int j = 0; j < 4; ++j) dst[j * 16] += acc[i][j][r];
      }
    }
}

extern "C" void kernel_launch(void* const* d_in, const int* in_sizes, int n_in,
                              void* d_out, int out_size, void* d_ws, size_t ws_size,
                              hipStream_t stream) {
  const float* x  = (const float*)d_in[0];
  const float* gw = (const float*)d_in[1];
  const float* w1 = (const float*)d_in[2];
  const float* w3 = (const float*)d_in[3];
  const float* w2 = (const float*)d_in[4];
  float* out = (float*)d_out;

  const size_t NW = (size_t)NE * HID * DIM;
  char* p = (char*)d_ws;
  unsigned short* w1b = (unsigned short*)p;  p += NW * 2;
  unsigned short* w3b = (unsigned short*)p;  p += NW * 2;
  unsigned short* w2b = (unsigned short*)p;  p += NW * 2;
  unsigned short* xb  = (unsigned short*)p;  p += (size_t)N_TOK * DIM * 2;
  int*      tokl = (int*)p;       p += (size_t)NE * N_TOK * 4;
  float*    wgtl = (float*)p;     p += (size_t)NE * N_TOK * 4;
  unsigned* eidx = (unsigned*)p;  p += (size_t)N_TOK * 4;
  float*    wts  = (float*)p;     p += (size_t)N_TOK * 4;
  int*      cnt  = (int*)p;       p += 256;   // [cntP|cntS|curP|curS] x 8
  unsigned short* Hs = (unsigned short*)p;
  size_t fixed = (size_t)(p - (char*)d_ws);
  if (ws_size < fixed) return;
  size_t avail = ws_size - fixed;

  const int cands[5] = {1536, 768, 512, 384, 256};
  int P = 0;
  for (int i = 0; i < 5; ++i)
    if ((size_t)(2 * N_TOK + 128) * cands[i] * 2 <= avail) { P = cands[i]; break; }
  if (!P) return;

  hipMemsetAsync(cnt, 0, 256, stream);

  int n4 = (int)(NW / 4);
  cvt3_kernel<<<3 * n4 / 256, 256, 0, stream>>>(w1, w3, w2, w1b, w3b, w2b, n4);

  gate1_kernel<<<N_TOK / 4, 256, 0, stream>>>(x, gw, xb, eidx, wts);
  gate2a_kernel<<<N_TOK / 1024, 256, 0, stream>>>(eidx, cnt);
  gate2b_kernel<<<N_TOK / 1024, 256, 0, stream>>>(eidx, wts, tokl, wgtl, cnt);

  int pass = 0;
  for (int h0 = 0; h0 < HID; h0 += P) {
    int NT = P / 64;
    ffn1_kernel<<<8 * MTS * NT, 256, 0, stream>>>(xb, w1b, w3b, tokl, wgtl, cnt, Hs, h0, P, NT);
    ffn2_kernel<<<8 * MTS * 4, 256, 0, stream>>>(Hs, w2b, tokl, cnt, out, h0, P, pass == 0, 0);
    ffn2_kernel<<<8 * MTS * 4, 256, 0, stream>>>(Hs, w2b, tokl, cnt, out, h0, P, 0, 1);
    ++pass;
  }
}